// Round 4
// baseline (800.685 us; speedup 1.0000x reference)
//
#include <hip/hip_runtime.h>
#include <hip/hip_bf16.h>

#define NN 100000   // nodes
#define NE 1600000  // edges
#define FF 64       // features
#define NC 10       // classes
#define NL 4        // layers
#define NB 128      // graphs
#define LDST 72     // LDS row stride in bf16 elems
#define SCAN_BLK 1024
#define NBLK_SCAN ((NN + SCAN_BLK - 1) / SCAN_BLK)   // 98
#define NBUCK ((NN + 127) / 128)                     // 782 buckets of 128 nodes

typedef __attribute__((ext_vector_type(8))) short short8;
typedef __attribute__((ext_vector_type(8))) unsigned short ushort8;
typedef __attribute__((ext_vector_type(4))) float f32x4;

static __device__ __forceinline__ unsigned short f2bf(float x) {
  unsigned int u = __float_as_uint(x);
  unsigned int r = (u + 0x7fffu + ((u >> 16) & 1u)) >> 16;
  return (unsigned short)r;
}
static __device__ __forceinline__ float bf2f(unsigned short u) {
  return __uint_as_float(((unsigned int)u) << 16);
}

// ============ x (f32) -> xb (bf16) ============
__global__ __launch_bounds__(256) void x2bf_kernel(const float* __restrict__ x,
                                                   unsigned short* __restrict__ xb) {
  int t = blockIdx.x * 256 + threadIdx.x;
  size_t base = (size_t)t * 8;
  float4 a = *(const float4*)(x + base);
  float4 b = *(const float4*)(x + base + 4);
  ushort8 u;
  u[0] = f2bf(a.x); u[1] = f2bf(a.y); u[2] = f2bf(a.z); u[3] = f2bf(a.w);
  u[4] = f2bf(b.x); u[5] = f2bf(b.y); u[6] = f2bf(b.z); u[7] = f2bf(b.w);
  *(ushort8*)(xb + base) = u;
}

// ============ all W [k][n] f32 -> Wt [mat][n][k] bf16 ============
__global__ __launch_bounds__(256) void convw_all(const float* __restrict__ W1s,
                                                 const float* __restrict__ W2s,
                                                 unsigned short* __restrict__ Wt) {
  int t = blockIdx.x * 256 + threadIdx.x;
  int mat = t >> 12, idx = t & 4095;
  int k = idx >> 6, n = idx & 63;
  int l = mat >> 1;
  const float* W = (mat & 1) ? (W2s + (size_t)l * FF * FF) : (W1s + (size_t)l * FF * FF);
  Wt[(size_t)mat * FF * FF + n * FF + k] = f2bf(W[k * FF + n]);
}

// ============ CSR build ============
__global__ __launch_bounds__(256) void hist_kernel(const int* __restrict__ dst,
                                                   int* __restrict__ deg) {
  int e = blockIdx.x * 256 + threadIdx.x;
  if (e < NE) atomicAdd(&deg[dst[e]], 1);
}

__global__ __launch_bounds__(256) void scan1(const int* __restrict__ deg,
                                             int* __restrict__ offs,
                                             int* __restrict__ partials) {
  __shared__ int sm[256];
  int t = threadIdx.x;
  int base = blockIdx.x * SCAN_BLK + t * 4;
  int v[4];
  #pragma unroll
  for (int j = 0; j < 4; ++j) {
    int i = base + j;
    v[j] = (i < NN) ? deg[i] : 0;
  }
  int s = v[0] + v[1] + v[2] + v[3];
  sm[t] = s;
  __syncthreads();
  for (int o = 1; o < 256; o <<= 1) {
    int x = (t >= o) ? sm[t - o] : 0;
    __syncthreads();
    sm[t] += x;
    __syncthreads();
  }
  int run = sm[t] - s;
  #pragma unroll
  for (int j = 0; j < 4; ++j) {
    int i = base + j;
    run += v[j];
    if (i < NN) offs[i + 1] = run;
  }
  if (t == 255) partials[blockIdx.x] = sm[255];
}

__global__ __launch_bounds__(128) void scan2(int* __restrict__ partials, int nblk) {
  __shared__ int sm[128];
  int t = threadIdx.x;
  int v = (t < nblk) ? partials[t] : 0;
  sm[t] = v;
  __syncthreads();
  for (int o = 1; o < 128; o <<= 1) {
    int x = (t >= o) ? sm[t - o] : 0;
    __syncthreads();
    sm[t] += x;
    __syncthreads();
  }
  if (t < nblk) partials[t] = sm[t] - v;
}

__global__ __launch_bounds__(256) void scan3(int* __restrict__ offs,
                                             const int* __restrict__ partials) {
  int b = blockIdx.x;
  int basev = partials[b];
  int base = b * SCAN_BLK + threadIdx.x * 4;
  #pragma unroll
  for (int j = 0; j < 4; ++j) {
    int i = base + j;
    if (i < NN) offs[i + 1] += basev;
  }
  if (b == 0 && threadIdx.x == 0) offs[0] = 0;
}

__global__ __launch_bounds__(256) void bcur_init(const int* __restrict__ offs,
                                                 int* __restrict__ bcur) {
  int b = blockIdx.x * 256 + threadIdx.x;
  if (b < NBUCK) bcur[b] = offs[b * 128];
}

// bin edges into bucket-ordered ebuf (packed dst<<32 | src); 782 sequential write streams
__global__ __launch_bounds__(256) void binB_kernel(const int* __restrict__ src,
                                                   const int* __restrict__ dst,
                                                   int* __restrict__ bcur,
                                                   unsigned long long* __restrict__ ebuf) {
  int e = blockIdx.x * 256 + threadIdx.x;
  if (e >= NE) return;
  int d = dst[e];
  int pos = atomicAdd(&bcur[d >> 7], 1);
  ebuf[pos] = ((unsigned long long)(unsigned)d << 32) | (unsigned)src[e];
}

// final csr fill: one block per bucket, LDS cursors, writes confined to 8KB window
__global__ __launch_bounds__(256) void fillC_kernel(
    const unsigned long long* __restrict__ ebuf, const int* __restrict__ offs,
    int* __restrict__ csr) {
  int b = blockIdx.x;
  int n0 = b << 7;
  int n1 = min(n0 + 128, NN);
  __shared__ int cur[128];
  int t = threadIdx.x;
  if (t < n1 - n0) cur[t] = offs[n0 + t];
  __syncthreads();
  int e0 = offs[n0], e1 = offs[n1];
  for (int i = e0 + t; i < e1; i += 256) {
    unsigned long long pk = ebuf[i];
    int s = (int)(pk & 0xffffffffull);
    int d = (int)(pk >> 32);
    int pos = atomicAdd(&cur[d - n0], 1);
    csr[pos] = s;
  }
}

// ============ gather: 4 nodes/wave, 16 lanes/node, ushort4 per lane ============
__global__ __launch_bounds__(256) void gather_kernel(
    const unsigned short* __restrict__ hb, const int* __restrict__ csr,
    const int* __restrict__ offs, unsigned short* __restrict__ aggb) {
  int t = threadIdx.x;
  int lane = t & 63;
  int g = lane >> 4, j = lane & 15;
  int node = blockIdx.x * 16 + (t >> 6) * 4 + g;
  if (node >= NN) return;
  int off = offs[node], end = offs[node + 1];
  ushort4 r = *(const ushort4*)(hb + (size_t)node * FF + j * 4);
  float a0 = bf2f(r.x), a1 = bf2f(r.y), a2 = bf2f(r.z), a3 = bf2f(r.w);
  int i = off;
  for (; i + 2 <= end; i += 2) {
    int s0 = csr[i], s1 = csr[i + 1];
    ushort4 r0 = *(const ushort4*)(hb + (size_t)s0 * FF + j * 4);
    ushort4 r1 = *(const ushort4*)(hb + (size_t)s1 * FF + j * 4);
    a0 += bf2f(r0.x) + bf2f(r1.x);
    a1 += bf2f(r0.y) + bf2f(r1.y);
    a2 += bf2f(r0.z) + bf2f(r1.z);
    a3 += bf2f(r0.w) + bf2f(r1.w);
  }
  if (i < end) {
    ushort4 r0 = *(const ushort4*)(hb + (size_t)csr[i] * FF + j * 4);
    a0 += bf2f(r0.x); a1 += bf2f(r0.y); a2 += bf2f(r0.z); a3 += bf2f(r0.w);
  }
  ushort4 u;
  u.x = f2bf(a0); u.y = f2bf(a1); u.z = f2bf(a2); u.w = f2bf(a3);
  *(ushort4*)(aggb + (size_t)node * FF + j * 4) = u;
}

// ============ fused MLP: hb = sig(sig(aggb @ W1) @ W2) ============
__global__ __launch_bounds__(256) void mlp2_kernel(
    const unsigned short* __restrict__ aggb, const unsigned short* __restrict__ Wt,
    unsigned short* __restrict__ hb, int n_rows) {
  __shared__ unsigned short uL[64 * LDST];
  __shared__ unsigned short vL[64 * LDST];
  __shared__ unsigned short w1L[64 * LDST];
  __shared__ unsigned short w2L[64 * LDST];
  int t = threadIdx.x;
  int row0 = blockIdx.x * 64;

  #pragma unroll
  for (int p = 0; p < 2; ++p) {
    int flat = p * 2048 + t * 8;
    int n = flat >> 6, k = flat & 63;
    *(ushort8*)(&w1L[n * LDST + k]) = *(const ushort8*)(Wt + flat);
    *(ushort8*)(&w2L[n * LDST + k]) = *(const ushort8*)(Wt + FF * FF + flat);
  }
  #pragma unroll
  for (int p = 0; p < 2; ++p) {
    int flat = p * 2048 + t * 8;
    int r = flat >> 6, c = flat & 63;
    int grow = row0 + r;
    ushort8 v = {0, 0, 0, 0, 0, 0, 0, 0};
    if (grow < n_rows) v = *(const ushort8*)(aggb + (size_t)grow * FF + c);
    *(ushort8*)(&uL[r * LDST + c]) = v;
  }
  __syncthreads();

  int lane = t & 63, w = t >> 6;
  int m = lane & 15, q = lane >> 4;

  f32x4 acc[4] = {{0,0,0,0},{0,0,0,0},{0,0,0,0},{0,0,0,0}};
  #pragma unroll
  for (int s = 0; s < 2; ++s) {
    short8 a = *(const short8*)(&uL[(w * 16 + m) * LDST + s * 32 + q * 8]);
    #pragma unroll
    for (int c4 = 0; c4 < 4; ++c4) {
      short8 b = *(const short8*)(&w1L[(c4 * 16 + m) * LDST + s * 32 + q * 8]);
      acc[c4] = __builtin_amdgcn_mfma_f32_16x16x32_bf16(a, b, acc[c4], 0, 0, 0);
    }
  }
  #pragma unroll
  for (int c4 = 0; c4 < 4; ++c4) {
    #pragma unroll
    for (int i = 0; i < 4; ++i) {
      int r = w * 16 + q * 4 + i;
      float sgv = 1.f / (1.f + __expf(-acc[c4][i]));
      vL[r * LDST + c4 * 16 + m] = f2bf(sgv);
    }
  }
  __syncthreads();

  f32x4 acc2[4] = {{0,0,0,0},{0,0,0,0},{0,0,0,0},{0,0,0,0}};
  #pragma unroll
  for (int s = 0; s < 2; ++s) {
    short8 a = *(const short8*)(&vL[(w * 16 + m) * LDST + s * 32 + q * 8]);
    #pragma unroll
    for (int c4 = 0; c4 < 4; ++c4) {
      short8 b = *(const short8*)(&w2L[(c4 * 16 + m) * LDST + s * 32 + q * 8]);
      acc2[c4] = __builtin_amdgcn_mfma_f32_16x16x32_bf16(a, b, acc2[c4], 0, 0, 0);
    }
  }
  #pragma unroll
  for (int c4 = 0; c4 < 4; ++c4) {
    #pragma unroll
    for (int i = 0; i < 4; ++i) {
      int grow = row0 + w * 16 + q * 4 + i;
      if (grow < n_rows) {
        float sgv = 1.f / (1.f + __expf(-acc2[c4][i]));
        hb[(size_t)grow * FF + c4 * 16 + m] = f2bf(sgv);
      }
    }
  }
}

// ============ pool + head ============
__global__ __launch_bounds__(256) void pool_kernel(
    const unsigned short* __restrict__ hb, const int* __restrict__ batch,
    float* __restrict__ xr) {
  int wave = (blockIdx.x * 256 + threadIdx.x) >> 6;
  int lane = threadIdx.x & 63;
  int r0 = wave * 64;
  if (r0 >= NN) return;
  int r1 = min(r0 + 64, NN);
  float acc = 0.f;
  int cur = batch[r0];
  for (int r = r0; r < r1; ++r) {
    int b = batch[r];
    if (b != cur) {
      unsafeAtomicAdd(&xr[(size_t)cur * FF + lane], acc);
      acc = 0.f; cur = b;
    }
    acc += bf2f(hb[(size_t)r * FF + lane]);
  }
  unsafeAtomicAdd(&xr[(size_t)cur * FF + lane], acc);
}

__global__ __launch_bounds__(64) void head_kernel(
    const float* __restrict__ xr, const float* __restrict__ fcw,
    const float* __restrict__ fcb, float* __restrict__ out) {
  int b = blockIdx.x, lane = threadIdx.x;
  float v = xr[(size_t)b * FF + lane];
  out[NB * NC + (size_t)b * FF + lane] = v;
  float logit[NC];
  #pragma unroll
  for (int c = 0; c < NC; ++c) {
    float s = v * fcw[c * FF + lane];
    #pragma unroll
    for (int o = 32; o > 0; o >>= 1) s += __shfl_xor(s, o, 64);
    logit[c] = s + fcb[c];
  }
  float mx = logit[0];
  #pragma unroll
  for (int c = 1; c < NC; ++c) mx = fmaxf(mx, logit[c]);
  float se = 0.f;
  #pragma unroll
  for (int c = 0; c < NC; ++c) se += expf(logit[c] - mx);
  float lse = logf(se);
  if (lane < NC) out[b * NC + lane] = logit[lane] - mx - lse;
}

extern "C" void kernel_launch(void* const* d_in, const int* in_sizes, int n_in,
                              void* d_out, int out_size, void* d_ws, size_t ws_size,
                              hipStream_t stream) {
  const float* x     = (const float*)d_in[0];
  const int*   ei    = (const int*)d_in[1];
  const int*   batch = (const int*)d_in[2];
  const float* W1s   = (const float*)d_in[3];
  const float* W2s   = (const float*)d_in[4];
  const float* fcw   = (const float*)d_in[5];
  const float* fcb   = (const float*)d_in[6];
  float* out = (float*)d_out;

  char* p = (char*)d_ws;
  unsigned short* xb   = (unsigned short*)p; p += (size_t)NN * FF * 2;  // 12.8 MB
  unsigned short* hb   = (unsigned short*)p; p += (size_t)NN * FF * 2;  // 12.8 MB
  unsigned short* aggb = (unsigned short*)p; p += (size_t)NN * FF * 2;  // 12.8 MB
  int* csr      = (int*)p;  p += (size_t)NE * 4;                        // 6.4 MB
  unsigned long long* ebuf = (unsigned long long*)p; p += (size_t)NE * 8; // 12.8 MB
  int* offs     = (int*)p;  p += (size_t)(NN + 4) * 4;
  int* deg      = (int*)p;  p += (size_t)NN * 4;
  int* bcur     = (int*)p;  p += (size_t)((NBUCK + 3) & ~3) * 4;
  int* partials = (int*)p;  p += 128 * 4;
  unsigned short* Wtall = (unsigned short*)p; p += (size_t)2 * NL * FF * FF * 2;
  float* xr     = (float*)p; p += (size_t)NB * FF * 4;

  const int* src = ei;
  const int* dst = ei + NE;

  // ---- prep ----
  x2bf_kernel<<<NN * FF / (256 * 8), 256, 0, stream>>>(x, xb);
  convw_all<<<2 * NL * FF * FF / 256, 256, 0, stream>>>(W1s, W2s, Wtall);

  // ---- CSR build (bucketed) ----
  hipMemsetAsync(deg, 0, (size_t)NN * 4, stream);
  hist_kernel<<<(NE + 255) / 256, 256, 0, stream>>>(dst, deg);
  scan1<<<NBLK_SCAN, 256, 0, stream>>>(deg, offs, partials);
  scan2<<<1, 128, 0, stream>>>(partials, NBLK_SCAN);
  scan3<<<NBLK_SCAN, 256, 0, stream>>>(offs, partials);
  bcur_init<<<(NBUCK + 255) / 256, 256, 0, stream>>>(offs, bcur);
  binB_kernel<<<(NE + 255) / 256, 256, 0, stream>>>(src, dst, bcur, ebuf);
  fillC_kernel<<<NBUCK, 256, 0, stream>>>(ebuf, offs, csr);

  // ---- layers ----
  int gemm_blocks = (NN + 63) / 64;
  int gather_blocks = (NN + 15) / 16;
  for (int l = 0; l < NL; ++l) {
    const unsigned short* hin = (l == 0) ? xb : hb;
    gather_kernel<<<gather_blocks, 256, 0, stream>>>(hin, csr, offs, aggb);
    mlp2_kernel<<<gemm_blocks, 256, 0, stream>>>(aggb, Wtall + (size_t)l * 2 * FF * FF, hb, NN);
  }

  hipMemsetAsync(xr, 0, (size_t)NB * FF * 4, stream);
  int pool_blocks = ((NN + 63) / 64 + 3) / 4;
  pool_kernel<<<pool_blocks, 256, 0, stream>>>(hb, batch, xr);
  head_kernel<<<NB, 64, 0, stream>>>(xr, fcw, fcb, out);
}

// Round 5
// 542.863 us; speedup vs baseline: 1.4749x; 1.4749x over previous
//
#include <hip/hip_runtime.h>
#include <hip/hip_bf16.h>

#define NN 100000   // nodes
#define NE 1600000  // edges
#define FF 64       // features
#define NC 10       // classes
#define NL 4        // layers
#define NB 128      // graphs
#define LDST 72     // LDS row stride in bf16 elems
#define SCAN_BLK 1024
#define NBLK_SCAN ((NN + SCAN_BLK - 1) / SCAN_BLK)   // 98

typedef __attribute__((ext_vector_type(8))) short short8;
typedef __attribute__((ext_vector_type(8))) unsigned short ushort8;
typedef __attribute__((ext_vector_type(4))) float f32x4;

static __device__ __forceinline__ unsigned short f2bf(float x) {
  unsigned int u = __float_as_uint(x);
  unsigned int r = (u + 0x7fffu + ((u >> 16) & 1u)) >> 16;
  return (unsigned short)r;
}
static __device__ __forceinline__ float bf2f(unsigned short u) {
  return __uint_as_float(((unsigned int)u) << 16);
}

// ============ x (f32) -> xb (bf16) ============
__global__ __launch_bounds__(256) void x2bf_kernel(const float* __restrict__ x,
                                                   unsigned short* __restrict__ xb) {
  int t = blockIdx.x * 256 + threadIdx.x;
  size_t base = (size_t)t * 8;
  float4 a = *(const float4*)(x + base);
  float4 b = *(const float4*)(x + base + 4);
  ushort8 u;
  u[0] = f2bf(a.x); u[1] = f2bf(a.y); u[2] = f2bf(a.z); u[3] = f2bf(a.w);
  u[4] = f2bf(b.x); u[5] = f2bf(b.y); u[6] = f2bf(b.z); u[7] = f2bf(b.w);
  *(ushort8*)(xb + base) = u;
}

// ============ all W [k][n] f32 -> Wt [mat][n][k] bf16 ============
__global__ __launch_bounds__(256) void convw_all(const float* __restrict__ W1s,
                                                 const float* __restrict__ W2s,
                                                 unsigned short* __restrict__ Wt) {
  int t = blockIdx.x * 256 + threadIdx.x;
  int mat = t >> 12, idx = t & 4095;
  int k = idx >> 6, n = idx & 63;
  int l = mat >> 1;
  const float* W = (mat & 1) ? (W2s + (size_t)l * FF * FF) : (W1s + (size_t)l * FF * FF);
  Wt[(size_t)mat * FF * FF + n * FF + k] = f2bf(W[k * FF + n]);
}

// ============ CSR build (R3 scheme: per-node cursors, low contention) ============
__global__ __launch_bounds__(256) void hist_kernel(const int* __restrict__ dst,
                                                   int* __restrict__ deg) {
  int e = blockIdx.x * 256 + threadIdx.x;
  if (e < NE) atomicAdd(&deg[dst[e]], 1);
}

__global__ __launch_bounds__(256) void scan1(const int* __restrict__ deg,
                                             int* __restrict__ offs,
                                             int* __restrict__ partials) {
  __shared__ int sm[256];
  int t = threadIdx.x;
  int base = blockIdx.x * SCAN_BLK + t * 4;
  int v[4];
  #pragma unroll
  for (int j = 0; j < 4; ++j) {
    int i = base + j;
    v[j] = (i < NN) ? deg[i] : 0;
  }
  int s = v[0] + v[1] + v[2] + v[3];
  sm[t] = s;
  __syncthreads();
  for (int o = 1; o < 256; o <<= 1) {
    int x = (t >= o) ? sm[t - o] : 0;
    __syncthreads();
    sm[t] += x;
    __syncthreads();
  }
  int run = sm[t] - s;
  #pragma unroll
  for (int j = 0; j < 4; ++j) {
    int i = base + j;
    run += v[j];
    if (i < NN) offs[i + 1] = run;
  }
  if (t == 255) partials[blockIdx.x] = sm[255];
}

__global__ __launch_bounds__(128) void scan2(int* __restrict__ partials, int nblk) {
  __shared__ int sm[128];
  int t = threadIdx.x;
  int v = (t < nblk) ? partials[t] : 0;
  sm[t] = v;
  __syncthreads();
  for (int o = 1; o < 128; o <<= 1) {
    int x = (t >= o) ? sm[t - o] : 0;
    __syncthreads();
    sm[t] += x;
    __syncthreads();
  }
  if (t < nblk) partials[t] = sm[t] - v;
}

__global__ __launch_bounds__(256) void scan3(int* __restrict__ offs,
                                             const int* __restrict__ partials) {
  int b = blockIdx.x;
  int basev = partials[b];
  int base = b * SCAN_BLK + threadIdx.x * 4;
  #pragma unroll
  for (int j = 0; j < 4; ++j) {
    int i = base + j;
    if (i < NN) offs[i + 1] += basev;
  }
  if (b == 0 && threadIdx.x == 0) offs[0] = 0;
}

__global__ __launch_bounds__(256) void cursor_init(const int* __restrict__ offs,
                                                   int* __restrict__ cursor) {
  int i = blockIdx.x * 256 + threadIdx.x;
  if (i < NN) cursor[i] = offs[i];
}

__global__ __launch_bounds__(256) void fill_kernel(const int* __restrict__ src,
                                                   const int* __restrict__ dst,
                                                   int* __restrict__ cursor,
                                                   int* __restrict__ csr) {
  int e = blockIdx.x * 256 + threadIdx.x;
  if (e >= NE) return;
  int pos = atomicAdd(&cursor[dst[e]], 1);
  __builtin_nontemporal_store(src[e], &csr[pos]);   // bypass TCC allocate on scattered 4B
}

// ============ gather: 4 nodes/wave, 16 lanes/node, ushort4 per lane ============
__global__ __launch_bounds__(256) void gather_kernel(
    const unsigned short* __restrict__ hb, const int* __restrict__ csr,
    const int* __restrict__ offs, unsigned short* __restrict__ aggb) {
  int t = threadIdx.x;
  int lane = t & 63;
  int g = lane >> 4, j = lane & 15;
  int node = blockIdx.x * 16 + (t >> 6) * 4 + g;
  if (node >= NN) return;
  int off = offs[node], end = offs[node + 1];
  ushort4 r = *(const ushort4*)(hb + (size_t)node * FF + j * 4);
  float a0 = bf2f(r.x), a1 = bf2f(r.y), a2 = bf2f(r.z), a3 = bf2f(r.w);
  int i = off;
  for (; i + 2 <= end; i += 2) {
    int s0 = csr[i], s1 = csr[i + 1];
    ushort4 r0 = *(const ushort4*)(hb + (size_t)s0 * FF + j * 4);
    ushort4 r1 = *(const ushort4*)(hb + (size_t)s1 * FF + j * 4);
    a0 += bf2f(r0.x) + bf2f(r1.x);
    a1 += bf2f(r0.y) + bf2f(r1.y);
    a2 += bf2f(r0.z) + bf2f(r1.z);
    a3 += bf2f(r0.w) + bf2f(r1.w);
  }
  if (i < end) {
    ushort4 r0 = *(const ushort4*)(hb + (size_t)csr[i] * FF + j * 4);
    a0 += bf2f(r0.x); a1 += bf2f(r0.y); a2 += bf2f(r0.z); a3 += bf2f(r0.w);
  }
  ushort4 u;
  u.x = f2bf(a0); u.y = f2bf(a1); u.z = f2bf(a2); u.w = f2bf(a3);
  *(ushort4*)(aggb + (size_t)node * FF + j * 4) = u;
}

// ============ fused MLP: hb = sig(sig(aggb @ W1) @ W2) ============
__global__ __launch_bounds__(256) void mlp2_kernel(
    const unsigned short* __restrict__ aggb, const unsigned short* __restrict__ Wt,
    unsigned short* __restrict__ hb, int n_rows) {
  __shared__ unsigned short uL[64 * LDST];
  __shared__ unsigned short vL[64 * LDST];
  __shared__ unsigned short w1L[64 * LDST];
  __shared__ unsigned short w2L[64 * LDST];
  int t = threadIdx.x;
  int row0 = blockIdx.x * 64;

  #pragma unroll
  for (int p = 0; p < 2; ++p) {
    int flat = p * 2048 + t * 8;
    int n = flat >> 6, k = flat & 63;
    *(ushort8*)(&w1L[n * LDST + k]) = *(const ushort8*)(Wt + flat);
    *(ushort8*)(&w2L[n * LDST + k]) = *(const ushort8*)(Wt + FF * FF + flat);
  }
  #pragma unroll
  for (int p = 0; p < 2; ++p) {
    int flat = p * 2048 + t * 8;
    int r = flat >> 6, c = flat & 63;
    int grow = row0 + r;
    ushort8 v = {0, 0, 0, 0, 0, 0, 0, 0};
    if (grow < n_rows) v = *(const ushort8*)(aggb + (size_t)grow * FF + c);
    *(ushort8*)(&uL[r * LDST + c]) = v;
  }
  __syncthreads();

  int lane = t & 63, w = t >> 6;
  int m = lane & 15, q = lane >> 4;

  f32x4 acc[4] = {{0,0,0,0},{0,0,0,0},{0,0,0,0},{0,0,0,0}};
  #pragma unroll
  for (int s = 0; s < 2; ++s) {
    short8 a = *(const short8*)(&uL[(w * 16 + m) * LDST + s * 32 + q * 8]);
    #pragma unroll
    for (int c4 = 0; c4 < 4; ++c4) {
      short8 b = *(const short8*)(&w1L[(c4 * 16 + m) * LDST + s * 32 + q * 8]);
      acc[c4] = __builtin_amdgcn_mfma_f32_16x16x32_bf16(a, b, acc[c4], 0, 0, 0);
    }
  }
  #pragma unroll
  for (int c4 = 0; c4 < 4; ++c4) {
    #pragma unroll
    for (int i = 0; i < 4; ++i) {
      int r = w * 16 + q * 4 + i;
      float sgv = 1.f / (1.f + __expf(-acc[c4][i]));
      vL[r * LDST + c4 * 16 + m] = f2bf(sgv);
    }
  }
  __syncthreads();

  f32x4 acc2[4] = {{0,0,0,0},{0,0,0,0},{0,0,0,0},{0,0,0,0}};
  #pragma unroll
  for (int s = 0; s < 2; ++s) {
    short8 a = *(const short8*)(&vL[(w * 16 + m) * LDST + s * 32 + q * 8]);
    #pragma unroll
    for (int c4 = 0; c4 < 4; ++c4) {
      short8 b = *(const short8*)(&w2L[(c4 * 16 + m) * LDST + s * 32 + q * 8]);
      acc2[c4] = __builtin_amdgcn_mfma_f32_16x16x32_bf16(a, b, acc2[c4], 0, 0, 0);
    }
  }
  #pragma unroll
  for (int c4 = 0; c4 < 4; ++c4) {
    #pragma unroll
    for (int i = 0; i < 4; ++i) {
      int grow = row0 + w * 16 + q * 4 + i;
      if (grow < n_rows) {
        float sgv = 1.f / (1.f + __expf(-acc2[c4][i]));
        hb[(size_t)grow * FF + c4 * 16 + m] = f2bf(sgv);
      }
    }
  }
}

// ============ pool + head ============
__global__ __launch_bounds__(256) void pool_kernel(
    const unsigned short* __restrict__ hb, const int* __restrict__ batch,
    float* __restrict__ xr) {
  int wave = (blockIdx.x * 256 + threadIdx.x) >> 6;
  int lane = threadIdx.x & 63;
  int r0 = wave * 64;
  if (r0 >= NN) return;
  int r1 = min(r0 + 64, NN);
  float acc = 0.f;
  int cur = batch[r0];
  for (int r = r0; r < r1; ++r) {
    int b = batch[r];
    if (b != cur) {
      unsafeAtomicAdd(&xr[(size_t)cur * FF + lane], acc);
      acc = 0.f; cur = b;
    }
    acc += bf2f(hb[(size_t)r * FF + lane]);
  }
  unsafeAtomicAdd(&xr[(size_t)cur * FF + lane], acc);
}

__global__ __launch_bounds__(64) void head_kernel(
    const float* __restrict__ xr, const float* __restrict__ fcw,
    const float* __restrict__ fcb, float* __restrict__ out) {
  int b = blockIdx.x, lane = threadIdx.x;
  float v = xr[(size_t)b * FF + lane];
  out[NB * NC + (size_t)b * FF + lane] = v;
  float logit[NC];
  #pragma unroll
  for (int c = 0; c < NC; ++c) {
    float s = v * fcw[c * FF + lane];
    #pragma unroll
    for (int o = 32; o > 0; o >>= 1) s += __shfl_xor(s, o, 64);
    logit[c] = s + fcb[c];
  }
  float mx = logit[0];
  #pragma unroll
  for (int c = 1; c < NC; ++c) mx = fmaxf(mx, logit[c]);
  float se = 0.f;
  #pragma unroll
  for (int c = 0; c < NC; ++c) se += expf(logit[c] - mx);
  float lse = logf(se);
  if (lane < NC) out[b * NC + lane] = logit[lane] - mx - lse;
}

extern "C" void kernel_launch(void* const* d_in, const int* in_sizes, int n_in,
                              void* d_out, int out_size, void* d_ws, size_t ws_size,
                              hipStream_t stream) {
  const float* x     = (const float*)d_in[0];
  const int*   ei    = (const int*)d_in[1];
  const int*   batch = (const int*)d_in[2];
  const float* W1s   = (const float*)d_in[3];
  const float* W2s   = (const float*)d_in[4];
  const float* fcw   = (const float*)d_in[5];
  const float* fcb   = (const float*)d_in[6];
  float* out = (float*)d_out;

  char* p = (char*)d_ws;
  unsigned short* xb   = (unsigned short*)p; p += (size_t)NN * FF * 2;  // 12.8 MB
  unsigned short* hb   = (unsigned short*)p; p += (size_t)NN * FF * 2;  // 12.8 MB
  unsigned short* aggb = (unsigned short*)p; p += (size_t)NN * FF * 2;  // 12.8 MB
  int* csr      = (int*)p;  p += (size_t)NE * 4;                        // 6.4 MB
  int* offs     = (int*)p;  p += (size_t)(NN + 4) * 4;
  int* deg      = (int*)p;  p += (size_t)NN * 4;                        // also cursor
  int* partials = (int*)p;  p += 128 * 4;
  unsigned short* Wtall = (unsigned short*)p; p += (size_t)2 * NL * FF * FF * 2;
  float* xr     = (float*)p; p += (size_t)NB * FF * 4;

  const int* src = ei;
  const int* dst = ei + NE;

  // ---- prep ----
  x2bf_kernel<<<NN * FF / (256 * 8), 256, 0, stream>>>(x, xb);
  convw_all<<<2 * NL * FF * FF / 256, 256, 0, stream>>>(W1s, W2s, Wtall);

  // ---- CSR build ----
  hipMemsetAsync(deg, 0, (size_t)NN * 4, stream);
  hist_kernel<<<(NE + 255) / 256, 256, 0, stream>>>(dst, deg);
  scan1<<<NBLK_SCAN, 256, 0, stream>>>(deg, offs, partials);
  scan2<<<1, 128, 0, stream>>>(partials, NBLK_SCAN);
  scan3<<<NBLK_SCAN, 256, 0, stream>>>(offs, partials);
  cursor_init<<<(NN + 255) / 256, 256, 0, stream>>>(offs, deg);
  fill_kernel<<<(NE + 255) / 256, 256, 0, stream>>>(src, dst, deg, csr);

  // ---- layers ----
  int gemm_blocks = (NN + 63) / 64;
  int gather_blocks = (NN + 15) / 16;
  for (int l = 0; l < NL; ++l) {
    const unsigned short* hin = (l == 0) ? xb : hb;
    gather_kernel<<<gather_blocks, 256, 0, stream>>>(hin, csr, offs, aggb);
    mlp2_kernel<<<gemm_blocks, 256, 0, stream>>>(aggb, Wtall + (size_t)l * 2 * FF * FF, hb, NN);
  }

  hipMemsetAsync(xr, 0, (size_t)NB * FF * 4, stream);
  int pool_blocks = ((NN + 63) / 64 + 3) / 4;
  pool_kernel<<<pool_blocks, 256, 0, stream>>>(hb, batch, xr);
  head_kernel<<<NB, 64, 0, stream>>>(xr, fcw, fcb, out);
}

// Round 6
// 486.922 us; speedup vs baseline: 1.6444x; 1.1149x over previous
//
#include <hip/hip_runtime.h>
#include <hip/hip_bf16.h>

#define NN 100000   // nodes
#define NE 1600000  // edges
#define FF 64       // features
#define NC 10       // classes
#define NL 4        // layers
#define NB 128      // graphs
#define LDST 72     // LDS row stride in bf16 elems (144 B = 9*16 B)
#define SCAN_BLK 1024
#define NBLK_SCAN ((NN + SCAN_BLK - 1) / SCAN_BLK)   // 98

typedef __attribute__((ext_vector_type(8))) short short8;
typedef __attribute__((ext_vector_type(8))) unsigned short ushort8;
typedef __attribute__((ext_vector_type(4))) float f32x4;

static __device__ __forceinline__ unsigned short f2bf(float x) {
  unsigned int u = __float_as_uint(x);
  unsigned int r = (u + 0x7fffu + ((u >> 16) & 1u)) >> 16;
  return (unsigned short)r;
}
static __device__ __forceinline__ float bf2f(unsigned short u) {
  return __uint_as_float(((unsigned int)u) << 16);
}

// ============ x (f32) -> xb (bf16) ============
__global__ __launch_bounds__(256) void x2bf_kernel(const float* __restrict__ x,
                                                   unsigned short* __restrict__ xb) {
  int t = blockIdx.x * 256 + threadIdx.x;
  size_t base = (size_t)t * 8;
  float4 a = *(const float4*)(x + base);
  float4 b = *(const float4*)(x + base + 4);
  ushort8 u;
  u[0] = f2bf(a.x); u[1] = f2bf(a.y); u[2] = f2bf(a.z); u[3] = f2bf(a.w);
  u[4] = f2bf(b.x); u[5] = f2bf(b.y); u[6] = f2bf(b.z); u[7] = f2bf(b.w);
  *(ushort8*)(xb + base) = u;
}

// ============ all W [k][n] f32 -> Wt [mat][n][k] bf16 ============
__global__ __launch_bounds__(256) void convw_all(const float* __restrict__ W1s,
                                                 const float* __restrict__ W2s,
                                                 unsigned short* __restrict__ Wt) {
  int t = blockIdx.x * 256 + threadIdx.x;
  int mat = t >> 12, idx = t & 4095;
  int k = idx >> 6, n = idx & 63;
  int l = mat >> 1;
  const float* W = (mat & 1) ? (W2s + (size_t)l * FF * FF) : (W1s + (size_t)l * FF * FF);
  Wt[(size_t)mat * FF * FF + n * FF + k] = f2bf(W[k * FF + n]);
}

// ============ CSR build ============
__global__ __launch_bounds__(256) void hist_kernel(const int* __restrict__ dst,
                                                   int* __restrict__ deg) {
  int e = blockIdx.x * 256 + threadIdx.x;
  if (e < NE) atomicAdd(&deg[dst[e]], 1);
}

__global__ __launch_bounds__(256) void scan1(const int* __restrict__ deg,
                                             int* __restrict__ offs,
                                             int* __restrict__ partials) {
  __shared__ int sm[256];
  int t = threadIdx.x;
  int base = blockIdx.x * SCAN_BLK + t * 4;
  int v[4];
  #pragma unroll
  for (int j = 0; j < 4; ++j) {
    int i = base + j;
    v[j] = (i < NN) ? deg[i] : 0;
  }
  int s = v[0] + v[1] + v[2] + v[3];
  sm[t] = s;
  __syncthreads();
  for (int o = 1; o < 256; o <<= 1) {
    int x = (t >= o) ? sm[t - o] : 0;
    __syncthreads();
    sm[t] += x;
    __syncthreads();
  }
  int run = sm[t] - s;
  #pragma unroll
  for (int j = 0; j < 4; ++j) {
    int i = base + j;
    run += v[j];
    if (i < NN) offs[i + 1] = run;
  }
  if (t == 255) partials[blockIdx.x] = sm[255];
}

__global__ __launch_bounds__(128) void scan2(int* __restrict__ partials, int nblk) {
  __shared__ int sm[128];
  int t = threadIdx.x;
  int v = (t < nblk) ? partials[t] : 0;
  sm[t] = v;
  __syncthreads();
  for (int o = 1; o < 128; o <<= 1) {
    int x = (t >= o) ? sm[t - o] : 0;
    __syncthreads();
    sm[t] += x;
    __syncthreads();
  }
  if (t < nblk) partials[t] = sm[t] - v;
}

// add block bases; also emit cursor[] = final offs[]
__global__ __launch_bounds__(256) void scan3(int* __restrict__ offs,
                                             const int* __restrict__ partials,
                                             int* __restrict__ cursor) {
  int b = blockIdx.x;
  int basev = partials[b];
  int base = b * SCAN_BLK + threadIdx.x * 4;
  #pragma unroll
  for (int j = 0; j < 4; ++j) {
    int i = base + j;
    if (i < NN) {
      int val = offs[i + 1] + basev;
      offs[i + 1] = val;
      if (i + 1 < NN) cursor[i + 1] = val;
    }
  }
  if (b == 0 && threadIdx.x == 0) { offs[0] = 0; cursor[0] = 0; }
}

__global__ __launch_bounds__(256) void fill_kernel(const int* __restrict__ src,
                                                   const int* __restrict__ dst,
                                                   int* __restrict__ cursor,
                                                   int* __restrict__ csr) {
  int e = blockIdx.x * 256 + threadIdx.x;
  if (e >= NE) return;
  int pos = atomicAdd(&cursor[dst[e]], 1);
  csr[pos] = src[e];
}

// ============ fused layer: hout = sig(sig((gather(hin)) @ W1) @ W2) ============
// 128 threads = 2 waves, 32 rows/block. Gather: 8 lanes/node (ushort8), 2 passes.
// uL rows are wave-private; GEMM1 output written back into uL (vL aliases uL).
__global__ __launch_bounds__(128) void layer_kernel(
    const unsigned short* __restrict__ hin, const int* __restrict__ csr,
    const int* __restrict__ offs, const unsigned short* __restrict__ Wt,
    unsigned short* __restrict__ hout) {
  __shared__ unsigned short uL[32 * LDST];
  __shared__ unsigned short w1L[64 * LDST];
  __shared__ unsigned short w2L[64 * LDST];
  int t = threadIdx.x;
  int row0 = blockIdx.x * 32;

  // stage both weight matrices (4096 bf16 each), already [n][k]
  #pragma unroll
  for (int p = 0; p < 4; ++p) {
    int flat = p * 1024 + t * 8;
    int n = flat >> 6, k = flat & 63;
    *(ushort8*)(&w1L[n * LDST + k]) = *(const ushort8*)(Wt + flat);
    *(ushort8*)(&w2L[n * LDST + k]) = *(const ushort8*)(Wt + FF * FF + flat);
  }

  int lane = t & 63, w = t >> 6;      // w in {0,1}
  int j = lane & 7;                   // feature block j*8..j*8+7
  int gnode = lane >> 3;              // 0..7

  // ---- gather phase: 2 passes x 8 nodes per wave -> 16 rows/wave ----
  #pragma unroll
  for (int pass = 0; pass < 2; ++pass) {
    int r = w * 16 + pass * 8 + gnode;
    int node = row0 + r;
    float a[8];
    #pragma unroll
    for (int kk = 0; kk < 8; ++kk) a[kk] = 0.f;
    if (node < NN) {
      ushort8 sv = *(const ushort8*)(hin + (size_t)node * FF + j * 8);
      #pragma unroll
      for (int kk = 0; kk < 8; ++kk) a[kk] = bf2f(sv[kk]);
      int i = offs[node], end = offs[node + 1];
      for (; i + 4 <= end; i += 4) {
        int s0 = csr[i], s1 = csr[i + 1], s2 = csr[i + 2], s3 = csr[i + 3];
        ushort8 r0 = *(const ushort8*)(hin + (size_t)s0 * FF + j * 8);
        ushort8 r1 = *(const ushort8*)(hin + (size_t)s1 * FF + j * 8);
        ushort8 r2 = *(const ushort8*)(hin + (size_t)s2 * FF + j * 8);
        ushort8 r3 = *(const ushort8*)(hin + (size_t)s3 * FF + j * 8);
        #pragma unroll
        for (int kk = 0; kk < 8; ++kk)
          a[kk] += (bf2f(r0[kk]) + bf2f(r1[kk])) + (bf2f(r2[kk]) + bf2f(r3[kk]));
      }
      for (; i < end; ++i) {
        ushort8 r0 = *(const ushort8*)(hin + (size_t)csr[i] * FF + j * 8);
        #pragma unroll
        for (int kk = 0; kk < 8; ++kk) a[kk] += bf2f(r0[kk]);
      }
    }
    ushort8 u;
    #pragma unroll
    for (int kk = 0; kk < 8; ++kk) u[kk] = f2bf(a[kk]);
    *(ushort8*)(&uL[r * LDST + j * 8]) = u;
  }
  __syncthreads();   // weights + gather rows visible

  int m = lane & 15, q = lane >> 4;

  // ---- GEMM1: sigmoid(uL @ W1) -> back into uL (wave-private rows) ----
  f32x4 acc[4] = {{0,0,0,0},{0,0,0,0},{0,0,0,0},{0,0,0,0}};
  #pragma unroll
  for (int s = 0; s < 2; ++s) {
    short8 a = *(const short8*)(&uL[(w * 16 + m) * LDST + s * 32 + q * 8]);
    #pragma unroll
    for (int c4 = 0; c4 < 4; ++c4) {
      short8 b = *(const short8*)(&w1L[(c4 * 16 + m) * LDST + s * 32 + q * 8]);
      acc[c4] = __builtin_amdgcn_mfma_f32_16x16x32_bf16(a, b, acc[c4], 0, 0, 0);
    }
  }
  #pragma unroll
  for (int c4 = 0; c4 < 4; ++c4) {
    #pragma unroll
    for (int i = 0; i < 4; ++i) {
      int r = w * 16 + q * 4 + i;     // C/D: row = q*4+reg, col = c4*16+m
      float sgv = 1.f / (1.f + __expf(-acc[c4][i]));
      uL[r * LDST + c4 * 16 + m] = f2bf(sgv);
    }
  }
  __syncthreads();

  // ---- GEMM2: sigmoid(uL @ W2) -> hout ----
  f32x4 acc2[4] = {{0,0,0,0},{0,0,0,0},{0,0,0,0},{0,0,0,0}};
  #pragma unroll
  for (int s = 0; s < 2; ++s) {
    short8 a = *(const short8*)(&uL[(w * 16 + m) * LDST + s * 32 + q * 8]);
    #pragma unroll
    for (int c4 = 0; c4 < 4; ++c4) {
      short8 b = *(const short8*)(&w2L[(c4 * 16 + m) * LDST + s * 32 + q * 8]);
      acc2[c4] = __builtin_amdgcn_mfma_f32_16x16x32_bf16(a, b, acc2[c4], 0, 0, 0);
    }
  }
  #pragma unroll
  for (int c4 = 0; c4 < 4; ++c4) {
    #pragma unroll
    for (int i = 0; i < 4; ++i) {
      int grow = row0 + w * 16 + q * 4 + i;
      if (grow < NN) {
        float sgv = 1.f / (1.f + __expf(-acc2[c4][i]));
        hout[(size_t)grow * FF + c4 * 16 + m] = f2bf(sgv);
      }
    }
  }
}

// ============ pool + head ============
__global__ __launch_bounds__(256) void pool_kernel(
    const unsigned short* __restrict__ hb, const int* __restrict__ batch,
    float* __restrict__ xr) {
  int wave = (blockIdx.x * 256 + threadIdx.x) >> 6;
  int lane = threadIdx.x & 63;
  int r0 = wave * 64;
  if (r0 >= NN) return;
  int r1 = min(r0 + 64, NN);
  float acc = 0.f;
  int cur = batch[r0];
  for (int r = r0; r < r1; ++r) {
    int b = batch[r];
    if (b != cur) {
      unsafeAtomicAdd(&xr[(size_t)cur * FF + lane], acc);
      acc = 0.f; cur = b;
    }
    acc += bf2f(hb[(size_t)r * FF + lane]);
  }
  unsafeAtomicAdd(&xr[(size_t)cur * FF + lane], acc);
}

__global__ __launch_bounds__(64) void head_kernel(
    const float* __restrict__ xr, const float* __restrict__ fcw,
    const float* __restrict__ fcb, float* __restrict__ out) {
  int b = blockIdx.x, lane = threadIdx.x;
  float v = xr[(size_t)b * FF + lane];
  out[NB * NC + (size_t)b * FF + lane] = v;
  float logit[NC];
  #pragma unroll
  for (int c = 0; c < NC; ++c) {
    float s = v * fcw[c * FF + lane];
    #pragma unroll
    for (int o = 32; o > 0; o >>= 1) s += __shfl_xor(s, o, 64);
    logit[c] = s + fcb[c];
  }
  float mx = logit[0];
  #pragma unroll
  for (int c = 1; c < NC; ++c) mx = fmaxf(mx, logit[c]);
  float se = 0.f;
  #pragma unroll
  for (int c = 0; c < NC; ++c) se += expf(logit[c] - mx);
  float lse = logf(se);
  if (lane < NC) out[b * NC + lane] = logit[lane] - mx - lse;
}

extern "C" void kernel_launch(void* const* d_in, const int* in_sizes, int n_in,
                              void* d_out, int out_size, void* d_ws, size_t ws_size,
                              hipStream_t stream) {
  const float* x     = (const float*)d_in[0];
  const int*   ei    = (const int*)d_in[1];
  const int*   batch = (const int*)d_in[2];
  const float* W1s   = (const float*)d_in[3];
  const float* W2s   = (const float*)d_in[4];
  const float* fcw   = (const float*)d_in[5];
  const float* fcb   = (const float*)d_in[6];
  float* out = (float*)d_out;

  char* p = (char*)d_ws;
  unsigned short* xb  = (unsigned short*)p; p += (size_t)NN * FF * 2;   // 12.8 MB
  unsigned short* hb0 = (unsigned short*)p; p += (size_t)NN * FF * 2;   // 12.8 MB
  unsigned short* hb1 = (unsigned short*)p; p += (size_t)NN * FF * 2;   // 12.8 MB
  int* csr      = (int*)p;  p += (size_t)NE * 4;                        // 6.4 MB
  int* offs     = (int*)p;  p += (size_t)(NN + 4) * 4;
  int* deg      = (int*)p;  p += (size_t)NN * 4;                        // cursor after scan3
  int* partials = (int*)p;  p += 128 * 4;
  unsigned short* Wtall = (unsigned short*)p; p += (size_t)2 * NL * FF * FF * 2;
  float* xr     = (float*)p; p += (size_t)NB * FF * 4;

  const int* src = ei;
  const int* dst = ei + NE;

  // ---- prep ----
  x2bf_kernel<<<NN * FF / (256 * 8), 256, 0, stream>>>(x, xb);
  convw_all<<<2 * NL * FF * FF / 256, 256, 0, stream>>>(W1s, W2s, Wtall);

  // ---- CSR build ----
  hipMemsetAsync(deg, 0, (size_t)NN * 4, stream);
  hist_kernel<<<(NE + 255) / 256, 256, 0, stream>>>(dst, deg);
  scan1<<<NBLK_SCAN, 256, 0, stream>>>(deg, offs, partials);
  scan2<<<1, 128, 0, stream>>>(partials, NBLK_SCAN);
  scan3<<<NBLK_SCAN, 256, 0, stream>>>(offs, partials, deg);
  fill_kernel<<<(NE + 255) / 256, 256, 0, stream>>>(src, dst, deg, csr);

  // ---- layers (fused gather+MLP, ping-pong) ----
  int layer_blocks = (NN + 31) / 32;   // 3125
  const unsigned short* hin = xb;
  unsigned short* bufs[2] = {hb0, hb1};
  for (int l = 0; l < NL; ++l) {
    unsigned short* hout = bufs[l & 1];
    layer_kernel<<<layer_blocks, 128, 0, stream>>>(hin, csr, offs,
        Wtall + (size_t)l * 2 * FF * FF, hout);
    hin = hout;
  }

  hipMemsetAsync(xr, 0, (size_t)NB * FF * 4, stream);
  int pool_blocks = ((NN + 63) / 64 + 3) / 4;
  pool_kernel<<<pool_blocks, 256, 0, stream>>>(bufs[(NL - 1) & 1], batch, xr);
  head_kernel<<<NB, 64, 0, stream>>>(xr, fcw, fcb, out);
}